// Round 5
// baseline (1443.656 us; speedup 1.0000x reference)
//
#include <hip/hip_runtime.h>

#define CH     16
#define HID    128
#define HWDIM  128
#define NB     32
#define NSTEPS 32

typedef float    f32x4 __attribute__((ext_vector_type(4)));
typedef _Float16 f16x4 __attribute__((ext_vector_type(4)));
typedef _Float16 f16x8 __attribute__((ext_vector_type(8)));

// compile-time ordering fence: per-wave DS ops complete in order in HW, so
// emission order == correctness for wave-private LDS (round-3 verified).
#define MEMBAR() asm volatile("" ::: "memory")

// ---------------------------------------------------------------------------
// Prepack weights into per-lane MFMA fragment order (fp16).
// A/B frag layout (16x16x32): lane l -> row/col = l&15, k = 8*(l>>4)+j.
// pw0: 16 frags, f = n*2+ks (n = hidden N-tile 0..7, ks = K-step, K pad 48->64)
// pw1: 4 frags,  f = ks (K over 128)
// ---------------------------------------------------------------------------
__global__ __launch_bounds__(256) void nca_prepack(
    const float* __restrict__ w0, const float* __restrict__ w1,
    _Float16* __restrict__ pw0, _Float16* __restrict__ pw1)
{
    const int tid = threadIdx.x;
    for (int s = tid; s < 16 * 64; s += 256) {
        const int f = s >> 6, l = s & 63;
        const int n = f >> 1, ks = f & 1;
        const int o = 16 * n + (l & 15);
        f16x8 v;
        #pragma unroll
        for (int j = 0; j < 8; ++j) {
            const int k = 32 * ks + 8 * (l >> 4) + j;
            v[j] = (_Float16)(k < 48 ? w0[o * 48 + k] : 0.f);
        }
        *reinterpret_cast<f16x8*>(&pw0[s * 8]) = v;
    }
    for (int s = tid; s < 4 * 64; s += 256) {
        const int ks = s >> 6, l = s & 63;
        f16x8 v;
        #pragma unroll
        for (int j = 0; j < 8; ++j) {
            const int k = 32 * ks + 8 * (l >> 4) + j;
            v[j] = (_Float16)w1[(l & 15) * 128 + k];
        }
        *reinterpret_cast<f16x8*>(&pw1[s * 8]) = v;
    }
}

// ---------------------------------------------------------------------------
// One NCA step.  1024 persistent blocks x 2 tiles (exactly 4 blocks/CU, no
// dispatch tail).  LDS pool (36864 B):
//   phase A: halo f32 pixel-major [18][18][20]            (25920 B, cross-wave)
//   phase B: per-wave 9216 B slices: ybuf[64][72]f16 -> hbuf[64][40]f16
//            (wave-private: no barriers, MEMBAR ordering only)
// Wave slices overlap the halo region -> THREE cross-wave barriers per tile:
//   (1) rep-WAR before halo staging, (2) halo staged, (3) perception reads
//   done before ybuf writes clobber halo.  (3) was missing in round 4 -> race.
// fc0 computed as H^T = W0*Y^T (operand swap) -> lane holds 4 consecutive
// hidden -> single b64 H-write.  fc1 as d^T = W1*H -> lane holds 4 consecutive
// channels -> epilogue writes f32x4 straight from accumulators (no dbuf).
// ---------------------------------------------------------------------------
__global__ __launch_bounds__(256, 4) void nca_step(
    const float* __restrict__ xin, float* __restrict__ xout,
    const float* __restrict__ mask,
    const _Float16* __restrict__ pw0, const float* __restrict__ fc0_b,
    const _Float16* __restrict__ pw1)
{
    __shared__ __align__(16) char pool[36864];
    float (*halo)[18][20] = reinterpret_cast<float(*)[18][20]>(pool);

    const int tid = threadIdx.x;
    const int w = tid >> 6, l = tid & 63;
    const int lr = l & 15, g = l >> 4;

    #pragma unroll 1
    for (int rep = 0; rep < 2; ++rep) {
        const int tile = blockIdx.x + rep * 1024;
        const int bz = tile >> 6;
        const int y0 = ((tile >> 3) & 7) * 16, x0 = (tile & 7) * 16;

        __syncthreads();     // (1) WAR: previous rep's slice use done before halo overwrite

        // ---- stage halo, pixel-major f32, pitch 20 floats ----
        for (int q = tid; q < 18 * 18 * 4; q += 256) {
            const int c4 = q & 3, p = q >> 2;
            const int ii = p / 18, jj = p - ii * 18;
            const int gy = y0 - 1 + ii, gx = x0 - 1 + jj;
            f32x4 v = {0.f, 0.f, 0.f, 0.f};
            if ((unsigned)gy < HWDIM && (unsigned)gx < HWDIM)
                v = *reinterpret_cast<const f32x4*>(
                    &xin[(((size_t)bz * HWDIM + gy) * HWDIM + gx) * CH + 4 * c4]);
            *reinterpret_cast<f32x4*>(&halo[ii][jj][4 * c4]) = v;
        }
        __syncthreads();     // (2) halo staged

        // ---- perception (f32), results as f16 in registers ----
        const int j = tid & 15, i = tid >> 4;
        const int li = i + 1, lj = j + 1;
        _Float16 idv[16], dxv[16], dyv[16];
        #pragma unroll
        for (int c4 = 0; c4 < 4; ++c4) {
            #define HLD(dy, dx) (*reinterpret_cast<const f32x4*>(&halo[li + (dy)][lj + (dx)][4 * c4]))
            const f32x4 n00 = HLD(-1,-1), n01 = HLD(-1,0), n02 = HLD(-1,1);
            const f32x4 n10 = HLD( 0,-1), n11 = HLD( 0,0), n12 = HLD( 0,1);
            const f32x4 n20 = HLD( 1,-1), n21 = HLD( 1,0), n22 = HLD( 1,1);
            #undef HLD
            const f32x4 gx = ((n02 - n00) + 2.f * (n12 - n10) + (n22 - n20)) * 0.125f;
            const f32x4 gy = ((n20 - n00) + 2.f * (n21 - n01) + (n22 - n02)) * 0.125f;
            #pragma unroll
            for (int e = 0; e < 4; ++e) {
                idv[4 * c4 + e] = (_Float16)n11[e];
                dxv[4 * c4 + e] = (_Float16)gx[e];
                dyv[4 * c4 + e] = (_Float16)gy[e];
            }
        }
        __syncthreads();     // (3) ALL waves' halo reads done before ybuf clobbers halo

        char* wreg = pool + w * 9216;      // this wave's private slice

        // ---- ybuf write: own row l, pitch 144 B; cols 0..47 = y, 48..63 = 0 ----
        {
            _Float16* yrow = reinterpret_cast<_Float16*>(wreg + l * 144);
            f16x8 v;
            #pragma unroll
            for (int e = 0; e < 8; ++e) v[e] = idv[e];
            *reinterpret_cast<f16x8*>(&yrow[0]) = v;
            #pragma unroll
            for (int e = 0; e < 8; ++e) v[e] = idv[8 + e];
            *reinterpret_cast<f16x8*>(&yrow[8]) = v;
            #pragma unroll
            for (int e = 0; e < 8; ++e) v[e] = dxv[e];
            *reinterpret_cast<f16x8*>(&yrow[16]) = v;
            #pragma unroll
            for (int e = 0; e < 8; ++e) v[e] = dxv[8 + e];
            *reinterpret_cast<f16x8*>(&yrow[24]) = v;
            #pragma unroll
            for (int e = 0; e < 8; ++e) v[e] = dyv[e];
            *reinterpret_cast<f16x8*>(&yrow[32]) = v;
            #pragma unroll
            for (int e = 0; e < 8; ++e) v[e] = dyv[8 + e];
            *reinterpret_cast<f16x8*>(&yrow[40]) = v;
            f16x8 z;
            #pragma unroll
            for (int e = 0; e < 8; ++e) z[e] = (_Float16)0.f;
            *reinterpret_cast<f16x8*>(&yrow[48]) = z;   // K-pad 48..63 = 0
            *reinterpret_cast<f16x8*>(&yrow[56]) = z;
        }
        MEMBAR();

        // ---- Y fragments (used as MFMA *B* operand; same lane layout) ----
        f16x8 afrag[8];
        #pragma unroll
        for (int t = 0; t < 4; ++t)
            #pragma unroll
            for (int ks = 0; ks < 2; ++ks)
                afrag[2 * t + ks] = *reinterpret_cast<const f16x8*>(
                    wreg + (16 * t + lr) * 144 + 64 * ks + 16 * g);
        MEMBAR();

        // ---- W1 fragments (A operand) + bias quads ----
        f16x8 b1f[4];
        #pragma unroll
        for (int ks = 0; ks < 4; ++ks)
            b1f[ks] = *reinterpret_cast<const f16x8*>(&pw1[(ks * 64 + l) * 8]);
        f32x4 bq[4][2];
        #pragma unroll
        for (int c = 0; c < 4; ++c)
            #pragma unroll
            for (int nl = 0; nl < 2; ++nl)
                bq[c][nl] = *reinterpret_cast<const f32x4*>(&fc0_b[32 * c + 16 * nl + 4 * g]);

        f32x4 dacc[4];
        #pragma unroll
        for (int t = 0; t < 4; ++t)
            #pragma unroll
            for (int r = 0; r < 4; ++r) dacc[t][r] = 0.f;

        // ---- 4 chunks of 32 hidden: H^T = relu(W0*Y^T + b), d^T += W1*H ----
        _Float16* hb = reinterpret_cast<_Float16*>(wreg);   // [64 px][40 h] f16
        #pragma unroll
        for (int c = 0; c < 4; ++c) {
            f16x8 b0f[4];
            #pragma unroll
            for (int q = 0; q < 4; ++q)
                b0f[q] = *reinterpret_cast<const f16x8*>(&pw0[((4 * c + q) * 64 + l) * 8]);
            #pragma unroll
            for (int nl = 0; nl < 2; ++nl) {
                #pragma unroll
                for (int t = 0; t < 4; ++t) {
                    f32x4 acc = {0.f, 0.f, 0.f, 0.f};
                    acc = __builtin_amdgcn_mfma_f32_16x16x32_f16(b0f[2*nl+0], afrag[2*t+0], acc, 0, 0, 0);
                    acc = __builtin_amdgcn_mfma_f32_16x16x32_f16(b0f[2*nl+1], afrag[2*t+1], acc, 0, 0, 0);
                    // D^T: row = hidden 16nl+4g+r, col = pixel 16t+lr
                    f16x4 hv;
                    #pragma unroll
                    for (int r = 0; r < 4; ++r)
                        hv[r] = (_Float16)fmaxf(acc[r] + bq[c][nl][r], 0.f);
                    *reinterpret_cast<f16x4*>(
                        reinterpret_cast<char*>(hb) + (16 * t + lr) * 80 + 32 * nl + 8 * g) = hv;
                }
            }
            MEMBAR();        // wave-private in-order DS: writes before reads
            #pragma unroll
            for (int t = 0; t < 4; ++t)
                dacc[t] = __builtin_amdgcn_mfma_f32_16x16x32_f16(
                    b1f[c],
                    *reinterpret_cast<const f16x8*>(
                        reinterpret_cast<const char*>(hb) + (16 * t + lr) * 80 + 16 * g),
                    dacc[t], 0, 0, 0);
            MEMBAR();        // WAR before next chunk's writes
        }

        // ---- epilogue straight from dacc: lane = (channel quad 4g, pixel 16t+lr) ----
        #pragma unroll
        for (int t = 0; t < 4; ++t) {
            const size_t pix = ((size_t)bz * HWDIM + (y0 + 4 * w + t)) * HWDIM + (x0 + lr);
            const float m = mask[pix];
            const f32x4 xi = *reinterpret_cast<const f32x4*>(&xin[pix * CH + 4 * g]);
            f32x4 d4 = dacc[t];
            if (g == 0) { d4[0] = 0.f; d4[1] = 0.f; d4[2] = 0.f; }   // ch 0..2 frozen
            f32x4 o;
            #pragma unroll
            for (int e = 0; e < 4; ++e) o[e] = xi[e] + d4[e] * m;
            *reinterpret_cast<f32x4*>(&xout[pix * CH + 4 * g]) = o;
        }
    }
}

// ---------------------------------------------------------------------------
// Mean-pool, 8-way split per batch: 256 blocks, partials summed in the head.
// ---------------------------------------------------------------------------
__global__ __launch_bounds__(256) void nca_pool(
    const float* __restrict__ xf, float* __restrict__ partial)
{
    __shared__ float red[256 * CH];
    const int b = blockIdx.x >> 3, part = blockIdx.x & 7, tid = threadIdx.x;
    float acc[CH];
    #pragma unroll
    for (int c = 0; c < CH; ++c) acc[c] = 0.f;
    const int p0 = part * 2048;
    for (int p = p0 + tid; p < p0 + 2048; p += 256) {
        const f32x4* px = reinterpret_cast<const f32x4*>(
            &xf[((size_t)b * HWDIM * HWDIM + p) * CH]);
        #pragma unroll
        for (int q = 0; q < 4; ++q) {
            const f32x4 v = px[q];
            acc[q*4+0] += v[0]; acc[q*4+1] += v[1];
            acc[q*4+2] += v[2]; acc[q*4+3] += v[3];
        }
    }
    #pragma unroll
    for (int c = 0; c < CH; ++c) red[tid * CH + c] = acc[c];
    __syncthreads();
    for (int off = 128; off > 0; off >>= 1) {
        if (tid < off) {
            #pragma unroll
            for (int c = 0; c < CH; ++c)
                red[tid * CH + c] += red[(tid + off) * CH + c];
        }
        __syncthreads();
    }
    if (tid < CH)
        partial[blockIdx.x * CH + tid] = red[tid];
}

// ---------------------------------------------------------------------------
__global__ __launch_bounds__(128) void nca_head(
    const float* __restrict__ partial,
    const float* __restrict__ fc2_w, const float* __restrict__ fc2_b,
    const float* __restrict__ fc3_w, const float* __restrict__ fc3_b,
    float* __restrict__ out)
{
    __shared__ float h2[HID];
    __shared__ float pl[CH];
    const int tid = threadIdx.x;
    for (int b = 0; b < NB; ++b) {
        if (tid < CH) {
            float s = 0.f;
            #pragma unroll
            for (int q = 0; q < 8; ++q) s += partial[(b * 8 + q) * CH + tid];
            pl[tid] = s * (1.f / (HWDIM * HWDIM));
        }
        __syncthreads();
        float h = fc2_b[tid];
        #pragma unroll
        for (int c = 0; c < CH; ++c) h += fc2_w[tid * CH + c] * pl[c];
        h2[tid] = fmaxf(h, 0.f);
        __syncthreads();
        if (tid < 13) {
            float o = fc3_b[tid];
            #pragma unroll
            for (int jj = 0; jj < HID; ++jj) o += fc3_w[tid * HID + jj] * h2[jj];
            out[b * 13 + tid] = o;
        }
        __syncthreads();
    }
}

// ---------------------------------------------------------------------------
extern "C" void kernel_launch(void* const* d_in, const int* in_sizes, int n_in,
                              void* d_out, int out_size, void* d_ws, size_t ws_size,
                              hipStream_t stream)
{
    const float* x     = (const float*)d_in[0];
    const float* masks = (const float*)d_in[1];
    const float* fc0_w = (const float*)d_in[2];
    const float* fc0_b = (const float*)d_in[3];
    const float* fc1_w = (const float*)d_in[4];
    const float* fc2_w = (const float*)d_in[5];
    const float* fc2_b = (const float*)d_in[6];
    const float* fc3_w = (const float*)d_in[7];
    const float* fc3_b = (const float*)d_in[8];

    float*    out     = (float*)d_out;
    float*    xf      = out + NB * 13;                             // output 1 region
    float*    buf0    = (float*)d_ws;                              // ping-pong state
    float*    partial = buf0 + (size_t)NB * HWDIM * HWDIM * CH;    // 256*16 f
    _Float16* pw0     = (_Float16*)(partial + 256 * CH);           // 16 KiB
    _Float16* pw1     = pw0 + 16 * 64 * 8;                         // 4 KiB

    nca_prepack<<<1, 256, 0, stream>>>(fc0_w, fc1_w, pw0, pw1);

    for (int s = 0; s < NSTEPS; ++s) {
        const float* in = (s == 0) ? x : ((s & 1) ? buf0 : xf);
        float* outp     = (s & 1) ? xf : buf0;
        nca_step<<<1024, 256, 0, stream>>>(in, outp,
            masks + (size_t)s * NB * HWDIM * HWDIM, pw0, fc0_b, pw1);
    }
    nca_pool<<<NB * 8, 256, 0, stream>>>(xf, partial);
    nca_head<<<1, 128, 0, stream>>>(partial, fc2_w, fc2_b, fc3_w, fc3_b, out);
}

// Round 6
// 1125.100 us; speedup vs baseline: 1.2831x; 1.2831x over previous
//
#include <hip/hip_runtime.h>

#define CH     16
#define HID    128
#define HWDIM  128
#define NB     32
#define NSTEPS 32

typedef float    f32x4 __attribute__((ext_vector_type(4)));
typedef _Float16 f16x4 __attribute__((ext_vector_type(4)));
typedef _Float16 f16x8 __attribute__((ext_vector_type(8)));

// compile-time ordering fence: per-wave DS ops complete in order in HW, so
// emission order == correctness for wave-private LDS (round-3 verified).
#define MEMBAR() asm volatile("" ::: "memory")

// ---------------------------------------------------------------------------
// Pack stochastic fire masks (exact 0.0/1.0 floats) into a 1-bit bitmap.
// One lane per pixel; __ballot produces 64 bits; lanes 0/32 store the halves.
// ---------------------------------------------------------------------------
__global__ __launch_bounds__(256) void nca_packmask(
    const float* __restrict__ masks, unsigned* __restrict__ bits)
{
    const int gidx = blockIdx.x * 256 + threadIdx.x;
    const float v = masks[gidx];
    const unsigned long long b = __ballot(v != 0.0f);
    const int l = threadIdx.x & 63;
    if ((l & 31) == 0) bits[gidx >> 5] = (unsigned)(b >> (l & 32));
}

// ---------------------------------------------------------------------------
// Prepack weights into per-lane MFMA fragment order (fp16).
// A/B frag layout (16x16x32): lane l -> row/col = l&15, k = 8*(l>>4)+j.
// pw0: 16 frags, f = n*2+ks (n = hidden N-tile 0..7, ks = K-step, K pad 48->64)
// pw1: 4 frags,  f = ks (K over 128)
// ---------------------------------------------------------------------------
__global__ __launch_bounds__(256) void nca_prepack(
    const float* __restrict__ w0, const float* __restrict__ w1,
    _Float16* __restrict__ pw0, _Float16* __restrict__ pw1)
{
    const int tid = threadIdx.x;
    for (int s = tid; s < 16 * 64; s += 256) {
        const int f = s >> 6, l = s & 63;
        const int n = f >> 1, ks = f & 1;
        const int o = 16 * n + (l & 15);
        f16x8 v;
        #pragma unroll
        for (int j = 0; j < 8; ++j) {
            const int k = 32 * ks + 8 * (l >> 4) + j;
            v[j] = (_Float16)(k < 48 ? w0[o * 48 + k] : 0.f);
        }
        *reinterpret_cast<f16x8*>(&pw0[s * 8]) = v;
    }
    for (int s = tid; s < 4 * 64; s += 256) {
        const int ks = s >> 6, l = s & 63;
        f16x8 v;
        #pragma unroll
        for (int j = 0; j < 8; ++j) {
            const int k = 32 * ks + 8 * (l >> 4) + j;
            v[j] = (_Float16)w1[(l & 15) * 128 + k];
        }
        *reinterpret_cast<f16x8*>(&pw1[s * 8]) = v;
    }
}

// ---------------------------------------------------------------------------
// One NCA step.  Grid dim3(8,8,32): one 16x16 tile per block -> x-tile -> XCD
// affinity is constant across steps (inter-step L2 reuse).  LDS pool 36864 B:
//   phase A: halo f32 pixel-major [18][18][20]          (25920 B, cross-wave)
//   phase B: per-wave 9216 B slices: ybuf[64 rows][144 B] -> hbuf[64][80 B]
//            -> dbuf[64][20]f32  (wave-private: MEMBAR ordering only)
// fc0 as H^T = W0*Y^T (lane holds 4 consecutive hidden -> b64 H-write);
// fc1 as d^T = W1*H; d transposed to thread-pixel layout via dbuf so the
// epilogue writes 4 sequential f32x4/thread and re-uses the center-pixel
// values kept in registers (NO global xin re-read, NO mask array read).
// ---------------------------------------------------------------------------
__global__ __launch_bounds__(256, 4) void nca_step(
    const float* __restrict__ xin, float* __restrict__ xout,
    const unsigned* __restrict__ bits,
    const _Float16* __restrict__ pw0, const float* __restrict__ fc0_b,
    const _Float16* __restrict__ pw1)
{
    __shared__ __align__(16) char pool[36864];
    float (*halo)[18][20] = reinterpret_cast<float(*)[18][20]>(pool);

    const int tid = threadIdx.x;
    const int w = tid >> 6, l = tid & 63;
    const int lr = l & 15, g = l >> 4;
    const int bz = blockIdx.z;
    const int y0 = blockIdx.y * 16, x0 = blockIdx.x * 16;

    // ---- stage halo, pixel-major f32, pitch 20 floats ----
    for (int q = tid; q < 18 * 18 * 4; q += 256) {
        const int c4 = q & 3, p = q >> 2;
        const int ii = p / 18, jj = p - ii * 18;
        const int gy = y0 - 1 + ii, gx = x0 - 1 + jj;
        f32x4 v = {0.f, 0.f, 0.f, 0.f};
        if ((unsigned)gy < HWDIM && (unsigned)gx < HWDIM)
            v = *reinterpret_cast<const f32x4*>(
                &xin[(((size_t)bz * HWDIM + gy) * HWDIM + gx) * CH + 4 * c4]);
        *reinterpret_cast<f32x4*>(&halo[ii][jj][4 * c4]) = v;
    }
    __syncthreads();     // halo staged

    // ---- perception (f32); keep center pixel in f32 regs; cast y -> f16 ----
    const int j = tid & 15, i = tid >> 4;
    const int li = i + 1, lj = j + 1;
    f32x4 xc[4];
    _Float16 idv[16], dxv[16], dyv[16];
    #pragma unroll
    for (int c4 = 0; c4 < 4; ++c4) {
        #define HLD(dy, dx) (*reinterpret_cast<const f32x4*>(&halo[li + (dy)][lj + (dx)][4 * c4]))
        const f32x4 n00 = HLD(-1,-1), n01 = HLD(-1,0), n02 = HLD(-1,1);
        const f32x4 n10 = HLD( 0,-1), n11 = HLD( 0,0), n12 = HLD( 0,1);
        const f32x4 n20 = HLD( 1,-1), n21 = HLD( 1,0), n22 = HLD( 1,1);
        #undef HLD
        const f32x4 gx = ((n02 - n00) + 2.f * (n12 - n10) + (n22 - n20)) * 0.125f;
        const f32x4 gy = ((n20 - n00) + 2.f * (n21 - n01) + (n22 - n02)) * 0.125f;
        xc[c4] = n11;
        #pragma unroll
        for (int e = 0; e < 4; ++e) {
            idv[4 * c4 + e] = (_Float16)n11[e];
            dxv[4 * c4 + e] = (_Float16)gx[e];
            dyv[4 * c4 + e] = (_Float16)gy[e];
        }
    }
    __syncthreads();     // ALL waves' halo reads done before ybuf clobbers halo

    char* wreg = pool + w * 9216;      // this wave's private slice

    // ---- ybuf write: own row l, pitch 144 B; cols 0..47 = y, 48..63 = 0 ----
    {
        _Float16* yrow = reinterpret_cast<_Float16*>(wreg + l * 144);
        f16x8 v;
        #pragma unroll
        for (int e = 0; e < 8; ++e) v[e] = idv[e];
        *reinterpret_cast<f16x8*>(&yrow[0]) = v;
        #pragma unroll
        for (int e = 0; e < 8; ++e) v[e] = idv[8 + e];
        *reinterpret_cast<f16x8*>(&yrow[8]) = v;
        #pragma unroll
        for (int e = 0; e < 8; ++e) v[e] = dxv[e];
        *reinterpret_cast<f16x8*>(&yrow[16]) = v;
        #pragma unroll
        for (int e = 0; e < 8; ++e) v[e] = dxv[8 + e];
        *reinterpret_cast<f16x8*>(&yrow[24]) = v;
        #pragma unroll
        for (int e = 0; e < 8; ++e) v[e] = dyv[e];
        *reinterpret_cast<f16x8*>(&yrow[32]) = v;
        #pragma unroll
        for (int e = 0; e < 8; ++e) v[e] = dyv[8 + e];
        *reinterpret_cast<f16x8*>(&yrow[40]) = v;
        f16x8 z;
        #pragma unroll
        for (int e = 0; e < 8; ++e) z[e] = (_Float16)0.f;
        *reinterpret_cast<f16x8*>(&yrow[48]) = z;   // K-pad 48..63 = 0
        *reinterpret_cast<f16x8*>(&yrow[56]) = z;
    }
    MEMBAR();

    // ---- Y fragments (MFMA B operand; same lane layout as A) ----
    f16x8 afrag[8];
    #pragma unroll
    for (int t = 0; t < 4; ++t)
        #pragma unroll
        for (int ks = 0; ks < 2; ++ks)
            afrag[2 * t + ks] = *reinterpret_cast<const f16x8*>(
                wreg + (16 * t + lr) * 144 + 64 * ks + 16 * g);
    MEMBAR();

    // ---- W1 fragments (A operand) + bias quads ----
    f16x8 b1f[4];
    #pragma unroll
    for (int ks = 0; ks < 4; ++ks)
        b1f[ks] = *reinterpret_cast<const f16x8*>(&pw1[(ks * 64 + l) * 8]);
    f32x4 bq[4][2];
    #pragma unroll
    for (int c = 0; c < 4; ++c)
        #pragma unroll
        for (int nl = 0; nl < 2; ++nl)
            bq[c][nl] = *reinterpret_cast<const f32x4*>(&fc0_b[32 * c + 16 * nl + 4 * g]);

    f32x4 dacc[4];
    #pragma unroll
    for (int t = 0; t < 4; ++t)
        #pragma unroll
        for (int r = 0; r < 4; ++r) dacc[t][r] = 0.f;

    // ---- 4 chunks of 32 hidden: H^T = relu(W0*Y^T + b), d^T += W1*H ----
    _Float16* hb = reinterpret_cast<_Float16*>(wreg);   // [64 px][80 B] f16
    #pragma unroll
    for (int c = 0; c < 4; ++c) {
        f16x8 b0f[4];
        #pragma unroll
        for (int q = 0; q < 4; ++q)
            b0f[q] = *reinterpret_cast<const f16x8*>(&pw0[((4 * c + q) * 64 + l) * 8]);
        #pragma unroll
        for (int nl = 0; nl < 2; ++nl) {
            #pragma unroll
            for (int t = 0; t < 4; ++t) {
                f32x4 acc = {0.f, 0.f, 0.f, 0.f};
                acc = __builtin_amdgcn_mfma_f32_16x16x32_f16(b0f[2*nl+0], afrag[2*t+0], acc, 0, 0, 0);
                acc = __builtin_amdgcn_mfma_f32_16x16x32_f16(b0f[2*nl+1], afrag[2*t+1], acc, 0, 0, 0);
                // D^T: row = hidden 16nl+4g+r, col = pixel 16t+lr
                f16x4 hv;
                #pragma unroll
                for (int r = 0; r < 4; ++r)
                    hv[r] = (_Float16)fmaxf(acc[r] + bq[c][nl][r], 0.f);
                *reinterpret_cast<f16x4*>(
                    reinterpret_cast<char*>(hb) + (16 * t + lr) * 80 + 32 * nl + 8 * g) = hv;
            }
        }
        MEMBAR();        // wave-private in-order DS: writes before reads
        #pragma unroll
        for (int t = 0; t < 4; ++t)
            dacc[t] = __builtin_amdgcn_mfma_f32_16x16x32_f16(
                b1f[c],
                *reinterpret_cast<const f16x8*>(
                    reinterpret_cast<const char*>(hb) + (16 * t + lr) * 80 + 16 * g),
                dacc[t], 0, 0, 0);
        MEMBAR();        // WAR before next chunk's writes
    }

    // ---- transpose d to thread-pixel layout via wave-private dbuf ----
    float* db = reinterpret_cast<float*>(wreg);         // [64 px][20] f32
    #pragma unroll
    for (int t = 0; t < 4; ++t)
        #pragma unroll
        for (int r = 0; r < 4; ++r)
            db[(16 * t + lr) * 20 + 4 * g + r] = dacc[t][r];
    MEMBAR();

    // ---- epilogue: center from regs, d from dbuf, mask from bitmap ----
    {
        const int p = (bz * HWDIM + (y0 + i)) * HWDIM + (x0 + j);
        const float m = ((bits[p >> 5] >> (p & 31)) & 1) ? 1.0f : 0.0f;
        const float* dp = db + (tid & 63) * 20;
        float* op = &xout[(size_t)p * CH];
        f32x4 o0 = xc[0];                       // ch 0..2 frozen (exact f32 copy)
        o0[3] += dp[3] * m;
        *reinterpret_cast<f32x4*>(&op[0]) = o0;
        #pragma unroll
        for (int q = 1; q < 4; ++q) {
            const f32x4 d4 = *reinterpret_cast<const f32x4*>(&dp[4 * q]);
            f32x4 o = xc[q];
            #pragma unroll
            for (int e = 0; e < 4; ++e) o[e] += d4[e] * m;
            *reinterpret_cast<f32x4*>(&op[4 * q]) = o;
        }
    }
}

// ---------------------------------------------------------------------------
// Mean-pool, 8-way split per batch: 256 blocks, partials summed in the head.
// ---------------------------------------------------------------------------
__global__ __launch_bounds__(256) void nca_pool(
    const float* __restrict__ xf, float* __restrict__ partial)
{
    __shared__ float red[256 * CH];
    const int b = blockIdx.x >> 3, part = blockIdx.x & 7, tid = threadIdx.x;
    float acc[CH];
    #pragma unroll
    for (int c = 0; c < CH; ++c) acc[c] = 0.f;
    const int p0 = part * 2048;
    for (int p = p0 + tid; p < p0 + 2048; p += 256) {
        const f32x4* px = reinterpret_cast<const f32x4*>(
            &xf[((size_t)b * HWDIM * HWDIM + p) * CH]);
        #pragma unroll
        for (int q = 0; q < 4; ++q) {
            const f32x4 v = px[q];
            acc[q*4+0] += v[0]; acc[q*4+1] += v[1];
            acc[q*4+2] += v[2]; acc[q*4+3] += v[3];
        }
    }
    #pragma unroll
    for (int c = 0; c < CH; ++c) red[tid * CH + c] = acc[c];
    __syncthreads();
    for (int off = 128; off > 0; off >>= 1) {
        if (tid < off) {
            #pragma unroll
            for (int c = 0; c < CH; ++c)
                red[tid * CH + c] += red[(tid + off) * CH + c];
        }
        __syncthreads();
    }
    if (tid < CH)
        partial[blockIdx.x * CH + tid] = red[tid];
}

// ---------------------------------------------------------------------------
__global__ __launch_bounds__(128) void nca_head(
    const float* __restrict__ partial,
    const float* __restrict__ fc2_w, const float* __restrict__ fc2_b,
    const float* __restrict__ fc3_w, const float* __restrict__ fc3_b,
    float* __restrict__ out)
{
    __shared__ float h2[HID];
    __shared__ float pl[CH];
    const int tid = threadIdx.x;
    for (int b = 0; b < NB; ++b) {
        if (tid < CH) {
            float s = 0.f;
            #pragma unroll
            for (int q = 0; q < 8; ++q) s += partial[(b * 8 + q) * CH + tid];
            pl[tid] = s * (1.f / (HWDIM * HWDIM));
        }
        __syncthreads();
        float h = fc2_b[tid];
        #pragma unroll
        for (int c = 0; c < CH; ++c) h += fc2_w[tid * CH + c] * pl[c];
        h2[tid] = fmaxf(h, 0.f);
        __syncthreads();
        if (tid < 13) {
            float o = fc3_b[tid];
            #pragma unroll
            for (int jj = 0; jj < HID; ++jj) o += fc3_w[tid * HID + jj] * h2[jj];
            out[b * 13 + tid] = o;
        }
        __syncthreads();
    }
}

// ---------------------------------------------------------------------------
extern "C" void kernel_launch(void* const* d_in, const int* in_sizes, int n_in,
                              void* d_out, int out_size, void* d_ws, size_t ws_size,
                              hipStream_t stream)
{
    const float* x     = (const float*)d_in[0];
    const float* masks = (const float*)d_in[1];
    const float* fc0_w = (const float*)d_in[2];
    const float* fc0_b = (const float*)d_in[3];
    const float* fc1_w = (const float*)d_in[4];
    const float* fc2_w = (const float*)d_in[5];
    const float* fc2_b = (const float*)d_in[6];
    const float* fc3_w = (const float*)d_in[7];
    const float* fc3_b = (const float*)d_in[8];

    float*    out     = (float*)d_out;
    float*    xf      = out + NB * 13;                             // output 1 region
    float*    buf0    = (float*)d_ws;                              // ping-pong state
    float*    partial = buf0 + (size_t)NB * HWDIM * HWDIM * CH;    // 256*16 f
    _Float16* pw0     = (_Float16*)(partial + 256 * CH);           // 16 KiB
    _Float16* pw1     = pw0 + 16 * 64 * 8;                         // 4 KiB
    unsigned* bits    = (unsigned*)(pw1 + 4 * 64 * 8);             // 2 MiB bitmap

    nca_prepack<<<1, 256, 0, stream>>>(fc0_w, fc1_w, pw0, pw1);
    nca_packmask<<<NSTEPS * NB * HWDIM * HWDIM / 256, 256, 0, stream>>>(masks, bits);

    dim3 grid(HWDIM / 16, HWDIM / 16, NB), block(256);
    for (int s = 0; s < NSTEPS; ++s) {
        const float* in = (s == 0) ? x : ((s & 1) ? buf0 : xf);
        float* outp     = (s & 1) ? xf : buf0;
        nca_step<<<grid, block, 0, stream>>>(in, outp,
            bits + (size_t)s * (NB * HWDIM * HWDIM / 32), pw0, fc0_b, pw1);
    }
    nca_pool<<<NB * 8, 256, 0, stream>>>(xf, partial);
    nca_head<<<1, 128, 0, stream>>>(partial, fc2_w, fc2_b, fc3_w, fc3_b, out);
}